// Round 15
// baseline (12290.938 us; speedup 1.0000x reference)
//
#include <hip/hip_runtime.h>

// Problem constants
#define BATCH 32
#define TFULL 1024
#define HDIM  256
#define G4    1024   // 4*HDIM
#define TC    128    // timestep chunk
#define NWG   512    // scan workgroups: 32 samples x 16 roles (2 per CU)

// =====================================================================
// GEMM (used once, for chunk 0's layer-0 input projection):
// xg[tl][b][n] = sum_k X[b, t0+tl, k] * W[n, k] + bia[n] + bib[n]
// =====================================================================
__global__ __launch_bounds__(512) void gemm_xg(
    const float* __restrict__ X, const float* __restrict__ W,
    const float* __restrict__ bia, const float* __restrict__ bib,
    float* __restrict__ xg, int K, int trows, int t0)
{
  __shared__ float Xs[16][128];
  __shared__ float Ws[16][128];
  const int tid = threadIdx.x;
  const int m0 = blockIdx.x * 128;
  const int n0 = blockIdx.y * 128;
  const int tx = tid & 15;
  const int ty = tid >> 4;

  float acc[4][8];
#pragma unroll
  for (int i = 0; i < 4; ++i)
#pragma unroll
    for (int j = 0; j < 8; ++j) acc[i][j] = 0.f;

  const int r  = tid >> 2;
  const int kq = tid & 3;
  const int m  = m0 + r;
  const int bX = m & 31;
  const int tl = m >> 5;
  const float* xrow = X + (bX * trows + t0 + tl) * K;
  const float* wrow = W + (n0 + r) * K;

  for (int kt = 0; kt < K; kt += 16) {
    float4 xv = *(const float4*)&xrow[kt + kq * 4];
    float4 wv = *(const float4*)&wrow[kt + kq * 4];
    Xs[kq * 4 + 0][r] = xv.x; Xs[kq * 4 + 1][r] = xv.y;
    Xs[kq * 4 + 2][r] = xv.z; Xs[kq * 4 + 3][r] = xv.w;
    Ws[kq * 4 + 0][r] = wv.x; Ws[kq * 4 + 1][r] = wv.y;
    Ws[kq * 4 + 2][r] = wv.z; Ws[kq * 4 + 3][r] = wv.w;
    __syncthreads();
#pragma unroll
    for (int k = 0; k < 16; ++k) {
      float4 xa = *(const float4*)&Xs[k][ty * 4];
      float4 wa = *(const float4*)&Ws[k][tx * 8];
      float4 wb = *(const float4*)&Ws[k][tx * 8 + 4];
      float xr[4] = {xa.x, xa.y, xa.z, xa.w};
      float wr[8] = {wa.x, wa.y, wa.z, wa.w, wb.x, wb.y, wb.z, wb.w};
#pragma unroll
      for (int i = 0; i < 4; ++i)
#pragma unroll
        for (int j = 0; j < 8; ++j)
          acc[i][j] = fmaf(xr[i], wr[j], acc[i][j]);
    }
    __syncthreads();
  }

  float bb[8];
#pragma unroll
  for (int j = 0; j < 8; ++j) {
    int n = n0 + tx * 8 + j;
    bb[j] = bia[n] + bib[n];
  }
#pragma unroll
  for (int i = 0; i < 4; ++i) {
    int mm = m0 + ty * 4 + i;
    int b = mm & 31, t = mm >> 5;
    float* dst = &xg[(size_t)(t * BATCH + b) * G4 + n0 + tx * 8];
    float4 v0 = make_float4(acc[i][0] + bb[0], acc[i][1] + bb[1],
                            acc[i][2] + bb[2], acc[i][3] + bb[3]);
    float4 v1 = make_float4(acc[i][4] + bb[4], acc[i][5] + bb[5],
                            acc[i][6] + bb[6], acc[i][7] + bb[7]);
    *(float4*)dst = v0;
    *(float4*)(dst + 4) = v1;
  }
}

// Pin 8 float4 into NAMED VGPR variables from one base pointer.
// All outputs defined at block end (spill-safe), opaque to remat.
#define PIN_LOAD8(A,B,C,D,E,F,G,H, PTR)                                \
  asm volatile(                                                        \
      "global_load_dwordx4 %0, %8, off\n\t"                            \
      "global_load_dwordx4 %1, %8, off offset:16\n\t"                  \
      "global_load_dwordx4 %2, %8, off offset:32\n\t"                  \
      "global_load_dwordx4 %3, %8, off offset:48\n\t"                  \
      "global_load_dwordx4 %4, %8, off offset:64\n\t"                  \
      "global_load_dwordx4 %5, %8, off offset:80\n\t"                  \
      "global_load_dwordx4 %6, %8, off offset:96\n\t"                  \
      "global_load_dwordx4 %7, %8, off offset:112\n\t"                 \
      "s_waitcnt vmcnt(0)"                                             \
      : "=&v"(A), "=&v"(B), "=&v"(C), "=&v"(D),                        \
        "=&v"(E), "=&v"(F), "=&v"(G), "=&v"(H)                         \
      : "v"(PTR) : "memory")

#define FMA4(ACC, WV, HV)                                              \
  ACC = fmaf((WV).x, (HV).x, ACC); ACC = fmaf((WV).y, (HV).y, ACC);    \
  ACC = fmaf((WV).z, (HV).z, ACC); ACC = fmaf((WV).w, (HV).w, ACC)

// 64-FMA dot of 16 named float4 weights against LDS quarter HP.
#define DOT16(ACC, W, HP)                                              \
  FMA4(ACC, W##0, (HP)[0]);  FMA4(ACC, W##1, (HP)[1]);                 \
  FMA4(ACC, W##2, (HP)[2]);  FMA4(ACC, W##3, (HP)[3]);                 \
  FMA4(ACC, W##4, (HP)[4]);  FMA4(ACC, W##5, (HP)[5]);                 \
  FMA4(ACC, W##6, (HP)[6]);  FMA4(ACC, W##7, (HP)[7]);                 \
  FMA4(ACC, W##8, (HP)[8]);  FMA4(ACC, W##9, (HP)[9]);                 \
  FMA4(ACC, W##a, (HP)[10]); FMA4(ACC, W##b, (HP)[11]);                \
  FMA4(ACC, W##c, (HP)[12]); FMA4(ACC, W##d, (HP)[13]);                \
  FMA4(ACC, W##e, (HP)[14]); FMA4(ACC, W##f, (HP)[15])

#define TAGOK(A,B,G)                                                   \
  ((__float_as_uint((A).y) == (G)) && (__float_as_uint((A).w) == (G)) && \
   (__float_as_uint((B).y) == (G)) && (__float_as_uint((B).w) == (G)))

__device__ __forceinline__ float sigm_f(float x) {
  return 1.f / (1.f + __expf(-x));
}
__device__ __forceinline__ float tanh_f(float x) {
  return 1.f - 2.f / (1.f + __expf(2.f * x));   // safe at +-inf
}

// =====================================================================
// Fused two-layer persistent scan (r12 structure: 2-step skew, 4-sync,
// T14-issued mailbox checks) + IN-SCAN GEMM for the NEXT chunk's xg.
//
// 512 WGs = 32 samples x 16 roles, 2 WGs/CU. WG (s,r) owns h columns
// [r*16, r*16+16) of both layers. Scan threads: gate gt = tid>>6, col
// jl = lane&15, k-quarter kq = lane>>4. Whh0/Whh1 pinned in 32 NAMED
// float4. Wih1 in swizzled LDS. h staged in stride-68 LDS quarters.
//
// In-scan GEMM (waves 2,3 = tid>=128, idle during the poll phase):
// each WG computes NEXT chunk's xg for exactly the region it consumes
// (sample s, role r's 64 gate-columns). Thread (gn, par): 16 groups
// J, group = 4 values tl = 8J+par+{0,2,4,6}; per iteration (i=8J+kc)
// one 64-k chunk x 4 tl = 256 FMA (W chunk reused across the 4 tl).
// Stores land in the post-sync_b slot of iteration 8J+7.
// SAFETY (single xg buffer, rolling overwrite): current[tl] is read
// (asm-pinned) at the TOP of iteration tl by the same WG; next[tl]
// (tl <= 8J+7) is stored after sync_b of iteration 8J+7 >= tl ->
// barrier-ordered after the read. WGs touch disjoint xg regions.
// Chunk 0's xg from one standalone gemm dispatch; chunk 7: no strips.
// =====================================================================
__global__ __launch_bounds__(256, 2) void lstm_scan2(
    float* __restrict__ xg,          // [TC][BATCH][G4] (read cur, write next)
    const float* __restrict__ Whh0,  // [G4][HDIM]
    const float* __restrict__ Wih1,  // [G4][HDIM]
    const float* __restrict__ Whh1,  // [G4][HDIM]
    const float* __restrict__ bih1, const float* __restrict__ bhh1,
    float* __restrict__ out,         // [B][TFULL][HDIM]
    float* __restrict__ mbA,         // [S][8 slots][512]
    float* __restrict__ mbB,         // [S][8 slots][512]
    float* __restrict__ cbA,         // [S][HDIM]
    float* __restrict__ cbB,         // [S][HDIM]
    int T0, int niter, int nL0,
    const float* __restrict__ enc,   // [B][TFULL][512]
    const float* __restrict__ Wih0,  // [G4][512]
    const float* __restrict__ bih0, const float* __restrict__ bhh0,
    int t0n, int do_gemm)
{
  const int w    = blockIdx.x;
  const int tid  = threadIdx.x;
  const int s    = w & 31;          // sample
  const int r    = w >> 5;          // role: columns [r*16, r*16+16)
  const int gt   = tid >> 6;        // gate type = wave id (i,f,g,o)
  const int lane = tid & 63;
  const int jl   = lane & 15;       // local column
  const int kq   = lane >> 4;       // k quarter (16-lane broadcast group)
  const int n    = gt * 256 + r * 16 + jl;
  const int swz  = tid & 15;        // Wih1 LDS slot swizzle

  __shared__ __align__(16) float wi_lds[256 * 64];  // 64 KB
  __shared__ __align__(16) float hAq[2][272];       // dbuf quarters, stride 68
  __shared__ __align__(16) float hBq[272];
  __shared__ float part0[64];
  __shared__ float part1[64];

  // ---- fill Wih1 slice into LDS (own row, swizzled slots) ----
  {
    const float4* src = (const float4*)(Wih1 + (size_t)n * HDIM + kq * 64);
    float* wb = &wi_lds[tid * 64];
#pragma unroll
    for (int q = 0; q < 16; ++q)
      *(float4*)&wb[(q ^ swz) << 2] = src[q];
  }

  // ---- pin Whh0 / Whh1 slices as 32 NAMED float4 locals ----
  float4 w00,w01,w02,w03,w04,w05,w06,w07,w08,w09,w0a,w0b,w0c,w0d,w0e,w0f;
  float4 w10,w11,w12,w13,w14,w15,w16,w17,w18,w19,w1a,w1b,w1c,w1d,w1e,w1f;
  {
    const float4* p0 = (const float4*)(Whh0 + (size_t)n * HDIM + kq * 64);
    const float4* p1 = (const float4*)(Whh1 + (size_t)n * HDIM + kq * 64);
    PIN_LOAD8(w00,w01,w02,w03,w04,w05,w06,w07, p0);
    PIN_LOAD8(w08,w09,w0a,w0b,w0c,w0d,w0e,w0f, p0 + 8);
    PIN_LOAD8(w10,w11,w12,w13,w14,w15,w16,w17, p1);
    PIN_LOAD8(w18,w19,w1a,w1b,w1c,w1d,w1e,w1f, p1 + 8);
  }
  const float bs1 = bih1[n] + bhh1[n];

  float cA = 0.f, cB = 0.f;
  if (tid < 16)              cA = cbA[s * HDIM + r * 16 + tid];
  if (tid >= 64 && tid < 80) cB = cbB[s * HDIM + r * 16 + (tid - 64)];

  // ---- in-scan GEMM setup (waves 2,3) ----
  const int tid2 = tid - 128;                      // valid for tid>=128
  const int gnl  = (tid2 >= 0) ? (tid2 >> 1) : 0;  // 0..63
  const int par  = (tid2 >= 0) ? (tid2 & 1) : 0;
  const int gn   = (gnl >> 4) * 256 + r * 16 + (gnl & 15);
  float bs0 = 0.f;
  const float* wgrow = Wih0 + (size_t)gn * 512;
  const float* xbase = enc + ((size_t)s * TFULL + t0n) * 512;
  if (do_gemm && tid >= 128) bs0 = bih0[gn] + bhh0[gn];
  float ga0 = 0.f, ga1 = 0.f, ga2 = 0.f, ga3 = 0.f;

  float* mA = mbA + (size_t)s * 8 * 512;
  float* mB = mbB + (size_t)s * 8 * 512;

  // ---- prologue: stage h_A[T0-2] (= A@(T0-1)) into old buffer [1] ----
  if (T0 >= 2 && tid < 64) {
    const unsigned gPr = (unsigned)(T0 - 1);
    const float4* sp = (const float4*)(mA + (size_t)(gPr & 7) * 512) + tid * 2;
    float4 A, B;
    for (;;) {
      asm volatile(
          "global_load_dwordx4 %0, %2, off sc0 sc1\n\t"
          "global_load_dwordx4 %1, %3, off sc0 sc1\n\t"
          "s_waitcnt vmcnt(0)"
          : "=&v"(A), "=&v"(B) : "v"(sp), "v"(sp + 1) : "memory");
      if (__all(TAGOK(A, B, gPr))) break;   // published by prev dispatch
    }
    *(float4*)&hAq[1][(tid >> 4) * 68 + ((4 * tid) & 63)] =
        make_float4(A.x, A.z, B.x, B.z);
  }
  __syncthreads();   // wi_lds + prologue ready

  for (int i = 0; i < niter; ++i) {
    const int t = T0 + i;
    const bool doL0   = (i < nL0);
    const bool doPoll = (i <= nL0);        // stage hA one iter past L0
    const bool doL1   = (t >= 2);
    const int  cur    = i & 1;
    const unsigned gA = (unsigned)t;       // A version consumed
    const unsigned gB = (unsigned)(t - 2); // B version consumed (2-skew)

    // ---- xv: asm-pinned read of current xg (top slot, all waves) ----
    float xv = 0.f;
    if (doL0 && lane < 16) {
      const float* xp = xg + (((size_t)(i * BATCH + s)) << 10) + n;
      asm volatile("global_load_dword %0, %1, off\n\t"
                   "s_waitcnt vmcnt(0)" : "=&v"(xv) : "v"(xp) : "memory");
    }

    // ---- T14 issue: wave0 -> A@t (checked after L1 dot) ----
    unsigned long long ap0 = 0, ap1 = 0, ap2 = 0, ap3 = 0;
    if (doPoll && tid < 64) {
      const unsigned long long* ap =
          (const unsigned long long*)(mA + (size_t)(gA & 7) * 512) +
          (size_t)tid * 4;
      ap0 = __hip_atomic_load(ap + 0, __ATOMIC_RELAXED, __HIP_MEMORY_SCOPE_AGENT);
      ap1 = __hip_atomic_load(ap + 1, __ATOMIC_RELAXED, __HIP_MEMORY_SCOPE_AGENT);
      ap2 = __hip_atomic_load(ap + 2, __ATOMIC_RELAXED, __HIP_MEMORY_SCOPE_AGENT);
      ap3 = __hip_atomic_load(ap + 3, __ATOMIC_RELAXED, __HIP_MEMORY_SCOPE_AGENT);
    }

    // ---- wave1: B@t-2 load+check+stage ----
    if (doL1 && tid >= 64 && tid < 128) {
      const int l2 = tid - 64;
      const unsigned long long* bp =
          (const unsigned long long*)(mB + (size_t)(gB & 7) * 512) +
          (size_t)l2 * 4;
      unsigned long long b0 = __hip_atomic_load(bp + 0, __ATOMIC_RELAXED, __HIP_MEMORY_SCOPE_AGENT);
      unsigned long long b1 = __hip_atomic_load(bp + 1, __ATOMIC_RELAXED, __HIP_MEMORY_SCOPE_AGENT);
      unsigned long long b2 = __hip_atomic_load(bp + 2, __ATOMIC_RELAXED, __HIP_MEMORY_SCOPE_AGENT);
      unsigned long long b3 = __hip_atomic_load(bp + 3, __ATOMIC_RELAXED, __HIP_MEMORY_SCOPE_AGENT);
      float h0, h1, h2, h3;
      bool ok = ((unsigned)(b0 >> 32) == gB) && ((unsigned)(b1 >> 32) == gB) &&
                ((unsigned)(b2 >> 32) == gB) && ((unsigned)(b3 >> 32) == gB);
      if (__all(ok)) {
        h0 = __uint_as_float((unsigned)b0);
        h1 = __uint_as_float((unsigned)b1);
        h2 = __uint_as_float((unsigned)b2);
        h3 = __uint_as_float((unsigned)b3);
      } else {
        const float4* sp = (const float4*)(mB + (size_t)(gB & 7) * 512) + l2 * 2;
        float4 A, B;
        for (;;) {
          asm volatile(
              "global_load_dwordx4 %0, %2, off sc0 sc1\n\t"
              "global_load_dwordx4 %1, %3, off sc0 sc1\n\t"
              "s_waitcnt vmcnt(0)"
              : "=&v"(A), "=&v"(B) : "v"(sp), "v"(sp + 1) : "memory");
          if (__all(TAGOK(A, B, gB))) break;
        }
        h0 = A.x; h1 = A.z; h2 = B.x; h3 = B.z;
      }
      *(float4*)&hBq[(l2 >> 4) * 68 + ((4 * l2) & 63)] =
          make_float4(h0, h1, h2, h3);
    }

    // ---- waves 2,3: in-scan GEMM strip (poll-phase shadow) ----
    if (do_gemm && tid >= 128 && i < TC) {
      const int kc = i & 7;
      if (kc == 0) { ga0 = 0.f; ga1 = 0.f; ga2 = 0.f; ga3 = 0.f; }
      const float* wp = wgrow + kc * 64;
      const float* x0 =
          xbase + ((size_t)((i >> 3) * 8 + par)) * 512 + kc * 64;
#pragma unroll
      for (int q = 0; q < 16; ++q) {
        float4 wv = *(const float4*)(wp + q * 4);
        float4 a0 = *(const float4*)(x0 + q * 4);
        float4 a1 = *(const float4*)(x0 + 1024 + q * 4);
        float4 a2 = *(const float4*)(x0 + 2048 + q * 4);
        float4 a3 = *(const float4*)(x0 + 3072 + q * 4);
        FMA4(ga0, wv, a0);
        FMA4(ga1, wv, a1);
        FMA4(ga2, wv, a2);
        FMA4(ga3, wv, a3);
      }
    }
    __syncthreads();   // sync_a: hBq ready; hAq[cur^1] from prev iter

    // ---- L1 dots (step t-2): Wih1 (LDS) . hA_old + Whh1 (regs) . hB ----
    if (doL1) {
      const float4* ha = (const float4*)&hAq[cur ^ 1][kq * 68];
      const float4* hb = (const float4*)&hBq[kq * 68];
      const float* wb = &wi_lds[tid * 64];
      float u = 0.f, v = 0.f;
#pragma unroll
      for (int q = 0; q < 16; ++q) {
        float4 wv = *(const float4*)&wb[(q ^ swz) << 2];
        FMA4(u, wv, ha[q]);
      }
      DOT16(v, w1, hb);
      float a = u + v;
      a += __shfl_xor(a, 16);
      a += __shfl_xor(a, 32);
      if (lane < 16) part1[gt * 16 + jl] = a + bs1;
    }
    __syncthreads();   // sync_b: part1 ready

    // ---- wave1: L1 finalize, publish B@t-1, out[t-2]
    // ---- wave0 (concurrent): check A tags, fallback poll, stage hAq[cur]
    // ---- waves 2,3 (concurrent): strip stores (group end)
    if (doL1 && tid >= 64 && tid < 80) {
      const int l = tid - 64;
      float ig = sigm_f(part1[l]);
      float fg = sigm_f(part1[16 + l]);
      float gv = tanh_f(part1[32 + l]);
      float og = sigm_f(part1[48 + l]);
      cB = fg * cB + ig * gv;
      float h = og * tanh_f(cB);
      unsigned long long pv =
          ((unsigned long long)(unsigned)(t - 1) << 32) |
          (unsigned long long)__float_as_uint(h);
      unsigned long long* pp =
          (unsigned long long*)(mB + (size_t)((t - 1) & 7) * 512) +
          (r * 16 + l);
      __hip_atomic_store(pp, pv, __ATOMIC_RELAXED, __HIP_MEMORY_SCOPE_AGENT);
      out[((size_t)s * TFULL + (t - 2)) * HDIM + r * 16 + l] = h;
    }
    if (doPoll && tid < 64) {
      float h0, h1, h2, h3;
      bool ok = ((unsigned)(ap0 >> 32) == gA) && ((unsigned)(ap1 >> 32) == gA) &&
                ((unsigned)(ap2 >> 32) == gA) && ((unsigned)(ap3 >> 32) == gA);
      if (__all(ok)) {
        h0 = __uint_as_float((unsigned)ap0);
        h1 = __uint_as_float((unsigned)ap1);
        h2 = __uint_as_float((unsigned)ap2);
        h3 = __uint_as_float((unsigned)ap3);
      } else {
        const float4* sp = (const float4*)(mA + (size_t)(gA & 7) * 512) + tid * 2;
        float4 A, B;
        for (;;) {
          asm volatile(
              "global_load_dwordx4 %0, %2, off sc0 sc1\n\t"
              "global_load_dwordx4 %1, %3, off sc0 sc1\n\t"
              "s_waitcnt vmcnt(0)"
              : "=&v"(A), "=&v"(B) : "v"(sp), "v"(sp + 1) : "memory");
          if (__all(TAGOK(A, B, gA))) break;
        }
        h0 = A.x; h1 = A.z; h2 = B.x; h3 = B.z;
      }
      *(float4*)&hAq[cur][(tid >> 4) * 68 + ((4 * tid) & 63)] =
          make_float4(h0, h1, h2, h3);
    }
    if (do_gemm && tid >= 128 && i < TC && (i & 7) == 7) {
      const int tl0 = (i >> 3) * 8 + par;
      const size_t base = ((size_t)tl0 * BATCH + s) * (size_t)G4 + gn;
      xg[base          ] = ga0 + bs0;
      xg[base +  65536 ] = ga1 + bs0;   // tl0+2  (2*BATCH*G4)
      xg[base + 131072 ] = ga2 + bs0;   // tl0+4
      xg[base + 196608 ] = ga3 + bs0;   // tl0+6
    }
    __syncthreads();   // sync_c: hAq[cur] staged

    // ---- L0 dot: Whh0 . hA (quarter broadcast, pinned weights) ----
    if (doL0) {
      const float4* hp = (const float4*)&hAq[cur][kq * 68];
      float a = 0.f;
      DOT16(a, w0, hp);
      a += __shfl_xor(a, 16);
      a += __shfl_xor(a, 32);
      if (lane < 16) part0[gt * 16 + jl] = a + xv;
    }
    __syncthreads();   // sync_d: part0 ready

    // ---- wave0 lanes: L0 finalize + publish A@t+1 ----
    if (doL0 && tid < 16) {
      float ig = sigm_f(part0[tid]);
      float fg = sigm_f(part0[16 + tid]);
      float gv = tanh_f(part0[32 + tid]);
      float og = sigm_f(part0[48 + tid]);
      cA = fg * cA + ig * gv;
      float h = og * tanh_f(cA);
      unsigned long long pv =
          ((unsigned long long)(gA + 1u) << 32) |
          (unsigned long long)__float_as_uint(h);
      unsigned long long* pp =
          (unsigned long long*)(mA + (size_t)((gA + 1u) & 7) * 512) +
          (r * 16 + tid);
      __hip_atomic_store(pp, pv, __ATOMIC_RELAXED, __HIP_MEMORY_SCOPE_AGENT);
    }
  }

  if (tid < 16)              cbA[s * HDIM + r * 16 + tid] = cA;
  if (tid >= 64 && tid < 80) cbB[s * HDIM + r * 16 + (tid - 64)] = cB;
}

// =====================================================================
// Host launcher
// =====================================================================
extern "C" void kernel_launch(void* const* d_in, const int* in_sizes, int n_in,
                              void* d_out, int out_size, void* d_ws, size_t ws_size,
                              hipStream_t stream) {
  (void)in_sizes; (void)n_in; (void)out_size; (void)ws_size;
  const float* enc  = (const float*)d_in[0];
  const float* Wih0 = (const float*)d_in[1];
  const float* Whh0 = (const float*)d_in[2];
  const float* bih0 = (const float*)d_in[3];
  const float* bhh0 = (const float*)d_in[4];
  const float* Wih1 = (const float*)d_in[5];
  const float* Whh1 = (const float*)d_in[6];
  const float* bih1 = (const float*)d_in[7];
  const float* bhh1 = (const float*)d_in[8];
  float* out = (float*)d_out;

  // workspace layout (floats)
  float* ws  = (float*)d_ws;
  float* xg  = ws;                     // TC*BATCH*G4 = 4,194,304
  float* st  = ws + 4194304;           // zeroed state region:
  float* mbA = st;                     //   32*8*512 = 131072
  float* mbB = st + 131072;            //   131072
  float* cbA = st + 262144;            //   8192
  float* cbB = st + 270336;            //   8192
  // zeroed total: 278528 floats

  hipMemsetAsync(st, 0, (size_t)278528 * 4, stream);

  // chunk 0's xg from the standalone GEMM; later chunks computed in-scan
  gemm_xg<<<dim3(32, 8), 512, 0, stream>>>(enc, Wih0, bih0, bhh0, xg,
                                           512, TFULL, 0);
  for (int ch = 0; ch < 8; ++ch) {
    lstm_scan2<<<NWG, 256, 0, stream>>>(xg, Whh0, Wih1, Whh1, bih1, bhh1,
                                        out, mbA, mbB, cbA, cbB,
                                        ch * TC, (ch == 7) ? TC + 2 : TC, TC,
                                        enc, Wih0, bih0, bhh0,
                                        (ch + 1) * TC, (ch < 7) ? 1 : 0);
  }
}

// Round 16
// 2987.926 us; speedup vs baseline: 4.1135x; 4.1135x over previous
//
#include <hip/hip_runtime.h>

// Problem constants
#define BATCH 32
#define TFULL 1024
#define HDIM  256
#define G4    1024   // 4*HDIM
#define TC    128    // timestep chunk
#define NWG   512    // scan workgroups: 32 samples x 16 roles (2 per CU)

// =====================================================================
// GEMM (layer-0 input projection only):
// xg[tl][b][n] = sum_k X[b, t0+tl, k] * W[n, k] + bia[n] + bib[n]
// =====================================================================
__global__ __launch_bounds__(512) void gemm_xg(
    const float* __restrict__ X, const float* __restrict__ W,
    const float* __restrict__ bia, const float* __restrict__ bib,
    float* __restrict__ xg, int K, int trows, int t0)
{
  __shared__ float Xs[16][128];
  __shared__ float Ws[16][128];
  const int tid = threadIdx.x;
  const int m0 = blockIdx.x * 128;
  const int n0 = blockIdx.y * 128;
  const int tx = tid & 15;
  const int ty = tid >> 4;

  float acc[4][8];
#pragma unroll
  for (int i = 0; i < 4; ++i)
#pragma unroll
    for (int j = 0; j < 8; ++j) acc[i][j] = 0.f;

  const int r  = tid >> 2;
  const int kq = tid & 3;
  const int m  = m0 + r;
  const int bX = m & 31;
  const int tl = m >> 5;
  const float* xrow = X + (bX * trows + t0 + tl) * K;
  const float* wrow = W + (n0 + r) * K;

  for (int kt = 0; kt < K; kt += 16) {
    float4 xv = *(const float4*)&xrow[kt + kq * 4];
    float4 wv = *(const float4*)&wrow[kt + kq * 4];
    Xs[kq * 4 + 0][r] = xv.x; Xs[kq * 4 + 1][r] = xv.y;
    Xs[kq * 4 + 2][r] = xv.z; Xs[kq * 4 + 3][r] = xv.w;
    Ws[kq * 4 + 0][r] = wv.x; Ws[kq * 4 + 1][r] = wv.y;
    Ws[kq * 4 + 2][r] = wv.z; Ws[kq * 4 + 3][r] = wv.w;
    __syncthreads();
#pragma unroll
    for (int k = 0; k < 16; ++k) {
      float4 xa = *(const float4*)&Xs[k][ty * 4];
      float4 wa = *(const float4*)&Ws[k][tx * 8];
      float4 wb = *(const float4*)&Ws[k][tx * 8 + 4];
      float xr[4] = {xa.x, xa.y, xa.z, xa.w};
      float wr[8] = {wa.x, wa.y, wa.z, wa.w, wb.x, wb.y, wb.z, wb.w};
#pragma unroll
      for (int i = 0; i < 4; ++i)
#pragma unroll
        for (int j = 0; j < 8; ++j)
          acc[i][j] = fmaf(xr[i], wr[j], acc[i][j]);
    }
    __syncthreads();
  }

  float bb[8];
#pragma unroll
  for (int j = 0; j < 8; ++j) {
    int n = n0 + tx * 8 + j;
    bb[j] = bia[n] + bib[n];
  }
#pragma unroll
  for (int i = 0; i < 4; ++i) {
    int mm = m0 + ty * 4 + i;
    int b = mm & 31, t = mm >> 5;
    float* dst = &xg[(size_t)(t * BATCH + b) * G4 + n0 + tx * 8];
    float4 v0 = make_float4(acc[i][0] + bb[0], acc[i][1] + bb[1],
                            acc[i][2] + bb[2], acc[i][3] + bb[3]);
    float4 v1 = make_float4(acc[i][4] + bb[4], acc[i][5] + bb[5],
                            acc[i][6] + bb[6], acc[i][7] + bb[7]);
    *(float4*)dst = v0;
    *(float4*)(dst + 4) = v1;
  }
}

// Pin 8 float4 into NAMED VGPR variables from one base pointer.
#define PIN_LOAD8(A,B,C,D,E,F,G,H, PTR)                                \
  asm volatile(                                                        \
      "global_load_dwordx4 %0, %8, off\n\t"                            \
      "global_load_dwordx4 %1, %8, off offset:16\n\t"                  \
      "global_load_dwordx4 %2, %8, off offset:32\n\t"                  \
      "global_load_dwordx4 %3, %8, off offset:48\n\t"                  \
      "global_load_dwordx4 %4, %8, off offset:64\n\t"                  \
      "global_load_dwordx4 %5, %8, off offset:80\n\t"                  \
      "global_load_dwordx4 %6, %8, off offset:96\n\t"                  \
      "global_load_dwordx4 %7, %8, off offset:112\n\t"                 \
      "s_waitcnt vmcnt(0)"                                             \
      : "=&v"(A), "=&v"(B), "=&v"(C), "=&v"(D),                        \
        "=&v"(E), "=&v"(F), "=&v"(G), "=&v"(H)                         \
      : "v"(PTR) : "memory")

#define FMA4(ACC, WV, HV)                                              \
  ACC = fmaf((WV).x, (HV).x, ACC); ACC = fmaf((WV).y, (HV).y, ACC);    \
  ACC = fmaf((WV).z, (HV).z, ACC); ACC = fmaf((WV).w, (HV).w, ACC)

// 64-FMA dot of 16 named float4 weights against LDS quarter HP.
#define DOT16(ACC, W, HP)                                              \
  FMA4(ACC, W##0, (HP)[0]);  FMA4(ACC, W##1, (HP)[1]);                 \
  FMA4(ACC, W##2, (HP)[2]);  FMA4(ACC, W##3, (HP)[3]);                 \
  FMA4(ACC, W##4, (HP)[4]);  FMA4(ACC, W##5, (HP)[5]);                 \
  FMA4(ACC, W##6, (HP)[6]);  FMA4(ACC, W##7, (HP)[7]);                 \
  FMA4(ACC, W##8, (HP)[8]);  FMA4(ACC, W##9, (HP)[9]);                 \
  FMA4(ACC, W##a, (HP)[10]); FMA4(ACC, W##b, (HP)[11]);                \
  FMA4(ACC, W##c, (HP)[12]); FMA4(ACC, W##d, (HP)[13]);                \
  FMA4(ACC, W##e, (HP)[14]); FMA4(ACC, W##f, (HP)[15])

__device__ __forceinline__ float sigm_f(float x) {
  return 1.f / (1.f + __expf(-x));
}
__device__ __forceinline__ float tanh_f(float x) {
  return 1.f - 2.f / (1.f + __expf(2.f * x));   // safe at +-inf
}

// =====================================================================
// Fused two-layer persistent scan (round-10 configuration — measured
// best: 333 us/dispatch). 512 WGs = 32 samples x 16 roles, 2 WGs/CU.
// WG (s,r) owns h columns [r*16, r*16+16) of both layers.
// Thread: gate gt = tid>>6, col jl = lane&15, k-quarter kq = lane>>4.
// Whh0/Whh1 slices: 32 NAMED float4 locals pinned via asm.
// Wih1 slice: LDS, per-thread 64-float row, XOR-swizzled slots.
// h staged in LDS quarters at stride 68 (conflict-free b128 reads).
// Mailbox protocol (tag-in-data, ring 8, MALL sc0 sc1).
// Per iteration i (t = T0+i):
//   wave1 ISSUES B@t-1 loads (relaxed agent atomics, checked late: T14)
//   wave0 polls A@t, stages hA                            [sync1]
//   all: L0 dot (Whh0.hA)                                 [sync2a]
//   wave0 lanes 0-15: L0 finalize, publish A@t+1 (early)
//   wave1: check B tags (re-poll if stale), stage hB      [sync2b]
//   all: L1 dots (Wih1.hA + Whh1.hB)                      [sync2c]
//   wave1 lanes 0-15: L1 finalize, publish B@t, write out[t-1]
// =====================================================================
__global__ __launch_bounds__(256, 2) void lstm_scan2(
    const float* __restrict__ xg0,   // [TC][BATCH][G4] layer-0, bias folded
    const float* __restrict__ Whh0,  // [G4][HDIM]
    const float* __restrict__ Wih1,  // [G4][HDIM]
    const float* __restrict__ Whh1,  // [G4][HDIM]
    const float* __restrict__ bih1, const float* __restrict__ bhh1,
    float* __restrict__ out,         // [B][TFULL][HDIM]
    float* __restrict__ mbA,         // [S][8 slots][512]
    float* __restrict__ mbB,         // [S][8 slots][512]
    float* __restrict__ cbA,         // [S][HDIM]
    float* __restrict__ cbB,         // [S][HDIM]
    int T0, int niter, int nL0)
{
  const int w    = blockIdx.x;
  const int tid  = threadIdx.x;
  const int s    = w & 31;          // sample
  const int r    = w >> 5;          // role: columns [r*16, r*16+16)
  const int gt   = tid >> 6;        // gate type = wave id (i,f,g,o)
  const int lane = tid & 63;
  const int jl   = lane & 15;       // local column
  const int kq   = lane >> 4;       // k quarter (16-lane broadcast group)
  const int n    = gt * 256 + r * 16 + jl;
  const int swz  = tid & 15;        // Wih1 LDS slot swizzle

  __shared__ __align__(16) float wi_lds[256 * 64];  // 64 KB
  __shared__ __align__(16) float hAq[4 * 68];       // quarters, stride 68
  __shared__ __align__(16) float hBq[4 * 68];
  __shared__ float part0[64];
  __shared__ float part1[64];

  // ---- fill Wih1 slice into LDS (own row, swizzled slots) ----
  {
    const float4* src = (const float4*)(Wih1 + (size_t)n * HDIM + kq * 64);
    float* wb = &wi_lds[tid * 64];
#pragma unroll
    for (int q = 0; q < 16; ++q)
      *(float4*)&wb[(q ^ swz) << 2] = src[q];
  }

  // ---- pin Whh0 / Whh1 slices as 32 NAMED float4 locals ----
  float4 w00,w01,w02,w03,w04,w05,w06,w07,w08,w09,w0a,w0b,w0c,w0d,w0e,w0f;
  float4 w10,w11,w12,w13,w14,w15,w16,w17,w18,w19,w1a,w1b,w1c,w1d,w1e,w1f;
  {
    const float4* p0 = (const float4*)(Whh0 + (size_t)n * HDIM + kq * 64);
    const float4* p1 = (const float4*)(Whh1 + (size_t)n * HDIM + kq * 64);
    PIN_LOAD8(w00,w01,w02,w03,w04,w05,w06,w07, p0);
    PIN_LOAD8(w08,w09,w0a,w0b,w0c,w0d,w0e,w0f, p0 + 8);
    PIN_LOAD8(w10,w11,w12,w13,w14,w15,w16,w17, p1);
    PIN_LOAD8(w18,w19,w1a,w1b,w1c,w1d,w1e,w1f, p1 + 8);
  }
  const float bs1 = bih1[n] + bhh1[n];

  float cA = 0.f, cB = 0.f;
  if (tid < 16)              cA = cbA[s * HDIM + r * 16 + tid];
  if (tid >= 64 && tid < 80) cB = cbB[s * HDIM + r * 16 + (tid - 64)];

  float* mA = mbA + (size_t)s * 8 * 512;
  float* mB = mbB + (size_t)s * 8 * 512;
  __syncthreads();   // wi_lds ready

  for (int i = 0; i < niter; ++i) {
    const int t = T0 + i;
    const bool doL0 = (i < nL0);
    const bool doL1 = (t > 0);
    const unsigned gA = (unsigned)t;        // A version consumed
    const unsigned gB = (unsigned)(t - 1);  // B version consumed

    float xv = 0.f;
    if (doL0 && lane < 16) xv = xg0[((size_t)(i * BATCH + s) << 10) + n];

    // ---- wave1: ISSUE B loads now, check after L0 (T14 split) ----
    unsigned long long bp0 = 0, bp1 = 0, bp2 = 0, bp3 = 0;
    if (doL1 && tid >= 64 && tid < 128) {
      const unsigned long long* bp =
          (const unsigned long long*)(mB + (size_t)(gB & 7) * 512) +
          (size_t)(tid - 64) * 4;
      bp0 = __hip_atomic_load(bp + 0, __ATOMIC_RELAXED, __HIP_MEMORY_SCOPE_AGENT);
      bp1 = __hip_atomic_load(bp + 1, __ATOMIC_RELAXED, __HIP_MEMORY_SCOPE_AGENT);
      bp2 = __hip_atomic_load(bp + 2, __ATOMIC_RELAXED, __HIP_MEMORY_SCOPE_AGENT);
      bp3 = __hip_atomic_load(bp + 3, __ATOMIC_RELAXED, __HIP_MEMORY_SCOPE_AGENT);
    }

    // ---- wave0: poll A@t (lane covers pairs 4l..4l+3), stage hA ----
    if (tid < 64) {
      const float4* sp = (const float4*)(mA + (size_t)(gA & 7) * 512) + tid * 2;
      float4 A, B;
      for (;;) {
        asm volatile(
            "global_load_dwordx4 %0, %2, off sc0 sc1\n\t"
            "global_load_dwordx4 %1, %3, off sc0 sc1\n\t"
            "s_waitcnt vmcnt(0)"
            : "=&v"(A), "=&v"(B) : "v"(sp), "v"(sp + 1) : "memory");
        bool ok = (__float_as_uint(A.y) == gA) && (__float_as_uint(A.w) == gA) &&
                  (__float_as_uint(B.y) == gA) && (__float_as_uint(B.w) == gA);
        if (__all(ok)) break;
      }
      *(float4*)&hAq[(tid >> 4) * 68 + ((4 * tid) & 63)] =
          make_float4(A.x, A.z, B.x, B.z);
    }
    __syncthreads();   // sync1: hA staged

    // ---- L0 dot: Whh0 . hA (quarter broadcast, reg weights) ----
    if (doL0) {
      const float4* hp = (const float4*)&hAq[kq * 68];
      float a = 0.f;
      DOT16(a, w0, hp);
      a += __shfl_xor(a, 16);
      a += __shfl_xor(a, 32);
      if (lane < 16) part0[gt * 16 + jl] = a + xv;
    }
    __syncthreads();   // sync2a: part0 ready

    // ---- wave0 lanes 0-15: L0 finalize + publish A@t+1 (early) ----
    if (doL0 && tid < 16) {
      float ig = sigm_f(part0[tid]);
      float fg = sigm_f(part0[16 + tid]);
      float gv = tanh_f(part0[32 + tid]);
      float og = sigm_f(part0[48 + tid]);
      cA = fg * cA + ig * gv;
      float h = og * tanh_f(cA);
      unsigned long long pv =
          ((unsigned long long)(gA + 1u) << 32) |
          (unsigned long long)__float_as_uint(h);
      unsigned long long* pp =
          (unsigned long long*)(mA + (size_t)((gA + 1u) & 7) * 512) +
          (r * 16 + tid);
      __hip_atomic_store(pp, pv, __ATOMIC_RELAXED, __HIP_MEMORY_SCOPE_AGENT);
    }

    // ---- wave1: check B tags, re-poll if stale, stage hB ----
    if (doL1 && tid >= 64 && tid < 128) {
      const int l2 = tid - 64;
      float h0, h1, h2, h3;
      bool ok = ((unsigned)(bp0 >> 32) == gB) && ((unsigned)(bp1 >> 32) == gB) &&
                ((unsigned)(bp2 >> 32) == gB) && ((unsigned)(bp3 >> 32) == gB);
      if (__all(ok)) {
        h0 = __uint_as_float((unsigned)bp0);
        h1 = __uint_as_float((unsigned)bp1);
        h2 = __uint_as_float((unsigned)bp2);
        h3 = __uint_as_float((unsigned)bp3);
      } else {
        const float4* sp = (const float4*)(mB + (size_t)(gB & 7) * 512) + l2 * 2;
        float4 A, B;
        for (;;) {
          asm volatile(
              "global_load_dwordx4 %0, %2, off sc0 sc1\n\t"
              "global_load_dwordx4 %1, %3, off sc0 sc1\n\t"
              "s_waitcnt vmcnt(0)"
              : "=&v"(A), "=&v"(B) : "v"(sp), "v"(sp + 1) : "memory");
          bool ok2 = (__float_as_uint(A.y) == gB) && (__float_as_uint(A.w) == gB) &&
                     (__float_as_uint(B.y) == gB) && (__float_as_uint(B.w) == gB);
          if (__all(ok2)) break;
        }
        h0 = A.x; h1 = A.z; h2 = B.x; h3 = B.z;
      }
      *(float4*)&hBq[(l2 >> 4) * 68 + ((4 * l2) & 63)] =
          make_float4(h0, h1, h2, h3);
    }
    __syncthreads();   // sync2b: hB staged

    // ---- L1 dots: Wih1 (LDS swizzled) . hA + Whh1 (regs) . hB ----
    if (doL1) {
      const float4* ha = (const float4*)&hAq[kq * 68];
      const float4* hb = (const float4*)&hBq[kq * 68];
      const float* wb = &wi_lds[tid * 64];
      float u = 0.f, v = 0.f;
#pragma unroll
      for (int q = 0; q < 16; ++q) {
        float4 wv = *(const float4*)&wb[(q ^ swz) << 2];
        FMA4(u, wv, ha[q]);
      }
      DOT16(v, w1, hb);
      float a = u + v;
      a += __shfl_xor(a, 16);
      a += __shfl_xor(a, 32);
      if (lane < 16) part1[gt * 16 + jl] = a + bs1;
    }
    __syncthreads();   // sync2c: part1 ready

    // ---- wave1 lanes 0-15: L1 finalize, publish B@t, write out ----
    if (doL1 && tid >= 64 && tid < 80) {
      const int l = tid - 64;
      float ig = sigm_f(part1[l]);
      float fg = sigm_f(part1[16 + l]);
      float gv = tanh_f(part1[32 + l]);
      float og = sigm_f(part1[48 + l]);
      cB = fg * cB + ig * gv;
      float h = og * tanh_f(cB);
      unsigned long long pv =
          ((unsigned long long)gA << 32) |
          (unsigned long long)__float_as_uint(h);
      unsigned long long* pp =
          (unsigned long long*)(mB + (size_t)(gA & 7) * 512) + (r * 16 + l);
      __hip_atomic_store(pp, pv, __ATOMIC_RELAXED, __HIP_MEMORY_SCOPE_AGENT);
      out[((size_t)s * TFULL + (t - 1)) * HDIM + r * 16 + l] = h;
    }
  }

  if (tid < 16)              cbA[s * HDIM + r * 16 + tid] = cA;
  if (tid >= 64 && tid < 80) cbB[s * HDIM + r * 16 + (tid - 64)] = cB;
}

// =====================================================================
// Host launcher
// =====================================================================
extern "C" void kernel_launch(void* const* d_in, const int* in_sizes, int n_in,
                              void* d_out, int out_size, void* d_ws, size_t ws_size,
                              hipStream_t stream) {
  (void)in_sizes; (void)n_in; (void)out_size; (void)ws_size;
  const float* enc  = (const float*)d_in[0];
  const float* Wih0 = (const float*)d_in[1];
  const float* Whh0 = (const float*)d_in[2];
  const float* bih0 = (const float*)d_in[3];
  const float* bhh0 = (const float*)d_in[4];
  const float* Wih1 = (const float*)d_in[5];
  const float* Whh1 = (const float*)d_in[6];
  const float* bih1 = (const float*)d_in[7];
  const float* bhh1 = (const float*)d_in[8];
  float* out = (float*)d_out;

  // workspace layout (floats)
  float* ws  = (float*)d_ws;
  float* xg  = ws;                     // TC*BATCH*G4 = 4,194,304
  float* st  = ws + 4194304;           // zeroed state region:
  float* mbA = st;                     //   32*8*512 = 131072
  float* mbB = st + 131072;            //   131072
  float* cbA = st + 262144;            //   8192
  float* cbB = st + 270336;            //   8192
  // zeroed total: 278528 floats

  hipMemsetAsync(st, 0, (size_t)278528 * 4, stream);

  for (int ch = 0; ch < 8; ++ch) {
    gemm_xg<<<dim3(32, 8), 512, 0, stream>>>(enc, Wih0, bih0, bhh0, xg,
                                             512, TFULL, ch * TC);
    lstm_scan2<<<NWG, 256, 0, stream>>>(xg, Whh0, Wih1, Whh1, bih1, bhh1,
                                        out, mbA, mbB, cbA, cbB,
                                        ch * TC, (ch == 7) ? TC + 1 : TC, TC);
  }
}